// Round 10
// baseline (2570.892 us; speedup 1.0000x reference)
//
#include <hip/hip_runtime.h>

#define TT 1500
#define BB 96
#define VV 128
#define LGT 256
#define LCAP 512
#define NEGF (-1.0e30f)
#define L2E 1.4426950408889634f
#define LN2F 0.6931471805599453f
#define HREF 30  // refresh cadence: 2*HREF=60 < 63-state ghost

// ---------------------------------------------------------------------------
// Kernel 1: greedy decode (unchanged).
// ---------------------------------------------------------------------------
__global__ __launch_bounds__(256) void decode_kernel(
    const float* __restrict__ acts, const int* __restrict__ act_lens,
    int* __restrict__ dec, int* __restrict__ dec_lens) {
  __shared__ int preds[TT];
  __shared__ int sc[256];
  const int b = blockIdx.x;
  const int tid = threadIdx.x;
  const int Tl = act_lens[b];
  for (int t = tid; t < Tl; t += 256) {
    const float4* r4 = (const float4*)(acts + ((size_t)t * BB + b) * VV);
    float best = -3.4e38f;
    int bi = 0;
#pragma unroll
    for (int i = 0; i < VV / 4; i++) {
      float4 v = r4[i];
      if (v.x > best) { best = v.x; bi = 4 * i; }
      if (v.y > best) { best = v.y; bi = 4 * i + 1; }
      if (v.z > best) { best = v.z; bi = 4 * i + 2; }
      if (v.w > best) { best = v.w; bi = 4 * i + 3; }
    }
    preds[t] = bi;
  }
  __syncthreads();

  int pv[6];
  bool fl[6];
  int cnt = 0;
#pragma unroll
  for (int j = 0; j < 6; j++) {
    int t = tid * 6 + j;
    bool valid = t < Tl;
    int p = valid ? preds[t] : 0;
    int pr = (t == 0) ? -1 : (valid ? preds[t - 1] : -1);
    bool f = valid && (p != 0) && (p != pr);
    pv[j] = p;
    fl[j] = f;
    cnt += f;
  }
  sc[tid] = cnt;
  __syncthreads();
  for (int off = 1; off < 256; off <<= 1) {
    int v = sc[tid];
    if (tid >= off) v += sc[tid - off];
    __syncthreads();
    sc[tid] = v;
    __syncthreads();
  }
  int pos = sc[tid] - cnt;  // exclusive prefix
  int total = sc[255];
  int* db = dec + (size_t)b * LCAP;
#pragma unroll
  for (int j = 0; j < 6; j++) {
    if (fl[j]) {
      if (pos < LCAP) db[pos] = pv[j];
      pos++;
    }
  }
  if (tid == 0) {
    if (total == 0) db[0] = 0;
    dec_lens[b] = max(1, min(total, LCAP));
  }
}

// ---------------------------------------------------------------------------
// Kernel 2: CTC, r8 structure (best known), templated ablation MODE:
//   MODE 0 real | 1 no-gather | 2 no-shuffle | 3 no-trans | 4 no-refresh
// Probes write to d_ws (live side effect, rule #17); only MODE 0 feeds d_out.
// ---------------------------------------------------------------------------
__device__ __forceinline__ float lse3f(float a0, float a1, float a2) {
  float m = fmaxf(fmaxf(a0, a1), a2);
  float dm = __builtin_amdgcn_fmed3f(a0, a1, a2) - m;
  float dn = fminf(fminf(a0, a1), a2) - m;
  float sm = 1.0f + __builtin_exp2f(dm) + __builtin_exp2f(dn);
  return m + __builtin_log2f(sm);
}

template <int R, int MODE>
__device__ __forceinline__ void ctc_core(
    const float* __restrict__ act_b, const int* __restrict__ lab, int Tl,
    int len, int S, float* __restrict__ xall, float* __restrict__ fin,
    float* __restrict__ ends, int outIdx) {
  const int tid = threadIdx.x;
  const int lane = tid & 63, wvL = tid >> 6;
  const int lm1 = (lane + 63) & 63;
  const int oS = (S + 3) >> 2;
  const int o0 = min(wvL * oS, S);
  const int o1 = min(o0 + oS, S);
  const int p0 = max(0, o0 - 63);

  float alpha[R];
  float gA[R], gB[R], gC[R], gD[R];
  int extk[R];
  bool al2[R];
#pragma unroll
  for (int r = 0; r < R; r++) {
    int s = p0 + lane * R + r;
    alpha[r] = NEGF;
    extk[r] = 0;
    al2[r] = false;
    gA[r] = gB[r] = gC[r] = gD[r] = 0.f;
    if (s < S && (s & 1)) {
      int i = s >> 1;
      int e = lab[i];
      extk[r] = e;
      al2[r] = (s >= 3) && (e != 0) && (e != lab[i - 1]);
    }
  }
  if (wvL == 0 && lane == 0) {
    alpha[0] = act_b[0] * L2E;
    alpha[1] = act_b[extk[1]] * L2E;
  }
  float pT1, pT2;
  if constexpr (MODE == 2) {
    pT1 = alpha[R - 1];
    pT2 = alpha[R - 2];
  } else {
    pT1 = __shfl(alpha[R - 1], lm1);
    pT2 = __shfl(alpha[R - 2], lm1);
  }

#define PREF(GN, ROW)                                        \
  if constexpr (MODE != 1) {                                 \
    const float* rp_ = act_b + (size_t)(ROW) * (BB * VV);    \
    _Pragma("unroll") for (int r = 0; r < R; r++)            \
        GN[r] = rp_[extk[r]];                                \
  }

#define UPD(DST, GV, A0, A1, A2)                                     \
  if constexpr (MODE == 3) {                                         \
    DST = (GV)*L2E + fmaxf(fmaxf((A0), (A1)), (A2));                 \
  } else {                                                           \
    DST = __builtin_fmaf((GV), L2E, lse3f((A0), (A1), (A2)));        \
  }

#define STEPK(GN)                                                    \
  {                                                                  \
    float pe1 = (lane != 0) ? pT1 : NEGF;                            \
    float pe2 = (lane != 0) ? pT2 : NEGF;                            \
    _Pragma("unroll") for (int r = R - 1; r >= 2; r--) {             \
      float a2_ = al2[r] ? alpha[r - 2] : NEGF;                      \
      UPD(alpha[r], GN[r], alpha[r], alpha[r - 1], a2_);             \
    }                                                                \
    {                                                                \
      float a2_ = al2[1] ? pe1 : NEGF;                               \
      UPD(alpha[1], GN[1], alpha[1], alpha[0], a2_);                 \
    }                                                                \
    {                                                                \
      float a2_ = al2[0] ? pe2 : NEGF;                               \
      UPD(alpha[0], GN[0], alpha[0], pe1, a2_);                      \
    }                                                                \
    if constexpr (MODE == 2) {                                       \
      pT1 = alpha[R - 1];                                            \
      pT2 = alpha[R - 2];                                            \
    } else {                                                         \
      pT1 = __shfl(alpha[R - 1], lm1);                               \
      pT2 = __shfl(alpha[R - 2], lm1);                               \
    }                                                                \
  }

#define REFRESH()                                      \
  {                                                    \
    __syncthreads();                                   \
    _Pragma("unroll") for (int r = 0; r < R; r++) {    \
      int s_ = p0 + lane * R + r;                      \
      if (s_ >= o0 && s_ < o1) xall[s_] = alpha[r];    \
    }                                                  \
    __syncthreads();                                   \
    _Pragma("unroll") for (int r = 0; r < R; r++) {    \
      int s_ = p0 + lane * R + r;                      \
      if (s_ < o0) alpha[r] = xall[s_];                \
    }                                                  \
    if constexpr (MODE == 2) {                         \
      pT1 = alpha[R - 1];                              \
      pT2 = alpha[R - 2];                              \
    } else {                                           \
      pT1 = __shfl(alpha[R - 1], lm1);                 \
      pT2 = __shfl(alpha[R - 2], lm1);                 \
    }                                                  \
  }

#define STAGE(UG, PG)                  \
  STEPK(UG);                           \
  PREF(PG, min(t + 3, Tl - 1));        \
  ++t;                                 \
  if constexpr (MODE != 4) {           \
    if (++since >= HREF) {             \
      if (t < Tl) REFRESH();           \
      since = 0;                       \
    }                                  \
  }                                    \
  if (t >= Tl) break;

  PREF(gB, min(1, Tl - 1));
  PREF(gC, min(2, Tl - 1));
  PREF(gD, min(3, Tl - 1));

  int t = 1, since = 0;
  while (t < Tl) {
    STAGE(gB, gA)
    STAGE(gC, gB)
    STAGE(gD, gC)
    STAGE(gA, gD)
  }
#undef STAGE
#undef REFRESH
#undef STEPK
#undef UPD
#undef PREF

  __syncthreads();
#pragma unroll
  for (int r = 0; r < R; r++) {
    int s = p0 + lane * R + r;
    if (s >= o0 && s < o1) {
      if (s == 2 * len) fin[0] = alpha[r];
      if (s == 2 * len - 1) fin[1] = alpha[r];
    }
  }
  __syncthreads();
  if (tid == 0) {
    float a = fin[0], c = fin[1];
    float m = fmaxf(a, c);
    float e = m + __builtin_log2f(__builtin_exp2f(a - m) + __builtin_exp2f(c - m));
    ends[outIdx] = e;
  }
}

template <int MODE>
__device__ __forceinline__ void ctc_dispatch(
    const float* __restrict__ acts, const int* __restrict__ labels_gt,
    const int* __restrict__ act_lens, const int* __restrict__ label_lens,
    const int* __restrict__ dec, const int* __restrict__ dec_lens,
    float* __restrict__ ends, float* __restrict__ xall,
    float* __restrict__ fin) {
  const int b = blockIdx.x >> 1;
  const int hyp = blockIdx.x & 1;
  const int Tl = act_lens[b];
  const int len = hyp ? dec_lens[b] : label_lens[b];
  const int* lab = hyp ? (dec + (size_t)b * LCAP) : (labels_gt + (size_t)b * LGT);
  const int S = 2 * len + 1;
  const float* act_b = acts + (size_t)b * VV;
  const int oS = (S + 3) >> 2;
  int Rd = (oS + 126) >> 6;
  if (Rd < 2) Rd = 2;
  const int oi = hyp * BB + b;
  if (Rd == 2)
    ctc_core<2, MODE>(act_b, lab, Tl, len, S, xall, fin, ends, oi);
  else if (Rd == 3)
    ctc_core<3, MODE>(act_b, lab, Tl, len, S, xall, fin, ends, oi);
  else if (Rd == 4)
    ctc_core<4, MODE>(act_b, lab, Tl, len, S, xall, fin, ends, oi);
  else
    ctc_core<5, MODE>(act_b, lab, Tl, len, S, xall, fin, ends, oi);
}

#define CTC_KERNEL(NAME, MODE)                                              \
  __global__ __launch_bounds__(256, 1) void NAME(                           \
      const float* __restrict__ acts, const int* __restrict__ labels_gt,    \
      const int* __restrict__ act_lens, const int* __restrict__ label_lens, \
      const int* __restrict__ dec, const int* __restrict__ dec_lens,        \
      float* __restrict__ ends) {                                           \
    __shared__ float xall[2 * LCAP + 1];                                    \
    __shared__ float fin[2];                                                \
    ctc_dispatch<MODE>(acts, labels_gt, act_lens, label_lens, dec,          \
                       dec_lens, ends, xall, fin);                          \
  }

CTC_KERNEL(ctc_v0_real, 0)
CTC_KERNEL(ctc_v1_nogather, 1)
CTC_KERNEL(ctc_v2_noshuffle, 2)
CTC_KERNEL(ctc_v3_notrans, 3)
CTC_KERNEL(ctc_v4_norefresh, 4)

// ---------------------------------------------------------------------------
// Kernel 3: out[b] = (end_hyp' - end_gt') * ln2 + 1.0  (log2-domain ends)
// ---------------------------------------------------------------------------
__global__ void final_kernel(const float* __restrict__ ends,
                             float* __restrict__ out) {
  int b = threadIdx.x;
  if (b < BB) out[b] = (ends[BB + b] - ends[b]) * LN2F + 1.0f;
}

extern "C" void kernel_launch(void* const* d_in, const int* in_sizes, int n_in,
                              void* d_out, int out_size, void* d_ws,
                              size_t ws_size, hipStream_t stream) {
  const float* acts = (const float*)d_in[0];
  const int* labels = (const int*)d_in[1];
  const int* act_lens = (const int*)d_in[2];
  const int* label_lens = (const int*)d_in[3];
  float* out = (float*)d_out;

  char* ws = (char*)d_ws;
  int* dec = (int*)ws;                                          // B*LCAP ints
  int* dec_lens = (int*)(ws + (size_t)BB * LCAP * 4);           // B ints
  float* ends = (float*)(ws + (size_t)BB * LCAP * 4 + BB * 4);  // 2*B floats
  float* endsP = ends + 2 * BB;                                 // probe sinks

  decode_kernel<<<dim3(BB), dim3(256), 0, stream>>>(acts, act_lens, dec, dec_lens);
  ctc_v0_real<<<dim3(2 * BB), dim3(256), 0, stream>>>(
      acts, labels, act_lens, label_lens, dec, dec_lens, ends);
  final_kernel<<<dim3(1), dim3(128), 0, stream>>>(ends, out);
  // --- diagnostic probes (write to ws only; timing sacrificial this round) ---
  ctc_v1_nogather<<<dim3(2 * BB), dim3(256), 0, stream>>>(
      acts, labels, act_lens, label_lens, dec, dec_lens, endsP + 0 * 2 * BB);
  ctc_v2_noshuffle<<<dim3(2 * BB), dim3(256), 0, stream>>>(
      acts, labels, act_lens, label_lens, dec, dec_lens, endsP + 1 * 2 * BB);
  ctc_v3_notrans<<<dim3(2 * BB), dim3(256), 0, stream>>>(
      acts, labels, act_lens, label_lens, dec, dec_lens, endsP + 2 * 2 * BB);
  ctc_v4_norefresh<<<dim3(2 * BB), dim3(256), 0, stream>>>(
      acts, labels, act_lens, label_lens, dec, dec_lens, endsP + 3 * 2 * BB);
}

// Round 12
// 648.601 us; speedup vs baseline: 3.9637x; 3.9637x over previous
//
#include <hip/hip_runtime.h>

#define TT 1500
#define BB 96
#define VV 128
#define LGT 256
#define LCAP 512
#define NEGF (-1.0e30f)
#define L2E 1.4426950408889634f
#define LN2F 0.6931471805599453f
#define HREF 30  // 2*HREF=60 < 62-state ghost
#define NW 16    // waves per CTC block

// ---------------------------------------------------------------------------
// Kernel 1: greedy decode (unchanged).
// ---------------------------------------------------------------------------
__global__ __launch_bounds__(256) void decode_kernel(
    const float* __restrict__ acts, const int* __restrict__ act_lens,
    int* __restrict__ dec, int* __restrict__ dec_lens) {
  __shared__ int preds[TT];
  __shared__ int sc[256];
  const int b = blockIdx.x;
  const int tid = threadIdx.x;
  const int Tl = act_lens[b];
  for (int t = tid; t < Tl; t += 256) {
    const float4* r4 = (const float4*)(acts + ((size_t)t * BB + b) * VV);
    float best = -3.4e38f;
    int bi = 0;
#pragma unroll
    for (int i = 0; i < VV / 4; i++) {
      float4 v = r4[i];
      if (v.x > best) { best = v.x; bi = 4 * i; }
      if (v.y > best) { best = v.y; bi = 4 * i + 1; }
      if (v.z > best) { best = v.z; bi = 4 * i + 2; }
      if (v.w > best) { best = v.w; bi = 4 * i + 3; }
    }
    preds[t] = bi;
  }
  __syncthreads();

  int pv[6];
  bool fl[6];
  int cnt = 0;
#pragma unroll
  for (int j = 0; j < 6; j++) {
    int t = tid * 6 + j;
    bool valid = t < Tl;
    int p = valid ? preds[t] : 0;
    int pr = (t == 0) ? -1 : (valid ? preds[t - 1] : -1);
    bool f = valid && (p != 0) && (p != pr);
    pv[j] = p;
    fl[j] = f;
    cnt += f;
  }
  sc[tid] = cnt;
  __syncthreads();
  for (int off = 1; off < 256; off <<= 1) {
    int v = sc[tid];
    if (tid >= off) v += sc[tid - off];
    __syncthreads();
    sc[tid] = v;
    __syncthreads();
  }
  int pos = sc[tid] - cnt;  // exclusive prefix
  int total = sc[255];
  int* db = dec + (size_t)b * LCAP;
#pragma unroll
  for (int j = 0; j < 6; j++) {
    if (fl[j]) {
      if (pos < LCAP) db[pos] = pv[j];
      pos++;
    }
  }
  if (tid == 0) {
    if (total == 0) db[0] = 0;
    dec_lens[b] = max(1, min(total, LCAP));
  }
}

// ---------------------------------------------------------------------------
// Kernel 2: CTC on raw acts, LOG2 domain (r5/r8 math, absmax 0.0), 16 waves,
// R=2 EVEN/ODD layout: p0 even, lane holds s0=p0+2*lane (blank) and s1=s0+1
// (label). Statically: blank has no skip & uniform logit (scalar load, no
// gather); label needs lse3 + 1 divergent gather; ONLY ONE bpermute/step
// (prev lane's a1). Ghost=62 states below owned; LDS refresh every 30 steps.
// Gathers 3 rows ahead via named-register 4-buffer rotation, STEP before PREF.
// ---------------------------------------------------------------------------
__global__ __launch_bounds__(1024, 1) void ctc_kernel(
    const float* __restrict__ acts, const int* __restrict__ labels_gt,
    const int* __restrict__ act_lens, const int* __restrict__ label_lens,
    const int* __restrict__ dec, const int* __restrict__ dec_lens,
    float* __restrict__ ends) {
  __shared__ float xall[2 * LCAP + 2];
  __shared__ float fin[2];
  const int b = blockIdx.x >> 1;
  const int hyp = blockIdx.x & 1;
  const int Tl = act_lens[b];
  const int len = hyp ? dec_lens[b] : label_lens[b];
  const int* lab = hyp ? (dec + (size_t)b * LCAP) : (labels_gt + (size_t)b * LGT);
  const int S = 2 * len + 1;
  const float* act_b = acts + (size_t)b * VV;  // acts[(t*BB + b)*VV + v]

  const int tid = threadIdx.x;
  const int lane = tid & 63, wv = tid >> 6;
  const int lm1 = (lane + 63) & 63;
  const int oS = 2 * ((S + 2 * NW - 1) / (2 * NW));  // even owned span
  const int Se = (S + 1) & ~1;
  const int o0 = min(wv * oS, Se);            // even
  const int o1 = min(o0 + oS, S);
  const int p0 = max(0, o0 - 62);             // even ghost bottom
  const int s0 = p0 + 2 * lane;               // blank state (even)
  const int s1 = s0 + 1;                      // label state (odd)

  int e1 = 0;
  bool skip = false;
  if (s1 < S) {
    int li = s1 >> 1;
    e1 = lab[li];
    if (s1 >= 3) skip = (e1 != 0) && (e1 != lab[li - 1]);
  }

  float a0 = NEGF, a1 = NEGF;
  if (wv == 0 && lane == 0) {
    a0 = act_b[0] * L2E;
    a1 = act_b[e1] * L2E;  // S >= 3 always (len >= 1)
  }
  float pT = __shfl(a1, lm1);

  float gL0, gL1, gL2, gL3;  // label logits (divergent gather)
  float gB0, gB1, gB2, gB3;  // blank logits (wave-uniform)

#define PREF(GL, GB, ROW)                                  \
  {                                                        \
    const float* rp_ = act_b + (size_t)(ROW) * (BB * VV);  \
    GB = rp_[0];                                           \
    GL = rp_[e1];                                          \
  }

#define STEPK(GL, GB)                                                     \
  {                                                                       \
    float pe = (lane != 0) ? pT : NEGF;                                   \
    /* blank (even): lse2(a0, pe) + GB */                                 \
    float m0 = fmaxf(a0, pe);                                             \
    float d0 = fminf(a0, pe) - m0;                                        \
    float n0 = m0 + __builtin_log2f(1.0f + __builtin_exp2f(d0));          \
    /* label (odd): lse3(a1, a0_old, skip?pe:NEG) + GL */                 \
    float c2 = skip ? pe : NEGF;                                          \
    float m1 = fmaxf(fmaxf(a1, a0), c2);                                  \
    float dm = __builtin_amdgcn_fmed3f(a1, a0, c2) - m1;                  \
    float dn = fminf(fminf(a1, a0), c2) - m1;                             \
    float n1 = m1 + __builtin_log2f(1.0f + __builtin_exp2f(dm) +          \
                                    __builtin_exp2f(dn));                 \
    a0 = __builtin_fmaf(GB, L2E, n0);                                     \
    a1 = __builtin_fmaf(GL, L2E, n1);                                     \
    pT = __shfl(a1, lm1);                                                 \
  }

#define REFRESH()                                        \
  {                                                      \
    __syncthreads();                                     \
    if (s0 >= o0 && s0 < o1) xall[s0] = a0;              \
    if (s1 >= o0 && s1 < o1) xall[s1] = a1;              \
    __syncthreads();                                     \
    if (s0 < o0) {                                       \
      a0 = xall[s0];                                     \
      a1 = (s1 < S) ? xall[s1] : NEGF;                   \
    }                                                    \
    pT = __shfl(a1, lm1);                                \
  }

#define STAGE(UL, UB, PL, PB)              \
  STEPK(UL, UB);                           \
  PREF(PL, PB, min(t + 3, Tl - 1));        \
  ++t;                                     \
  if (++since >= HREF) {                   \
    if (t < Tl) REFRESH();                 \
    since = 0;                             \
  }                                        \
  if (t >= Tl) break;

  PREF(gL1, gB1, min(1, Tl - 1));
  PREF(gL2, gB2, min(2, Tl - 1));
  PREF(gL3, gB3, min(3, Tl - 1));

  int t = 1, since = 0;
  while (t < Tl) {
    STAGE(gL1, gB1, gL0, gB0)
    STAGE(gL2, gB2, gL1, gB1)
    STAGE(gL3, gB3, gL2, gB2)
    STAGE(gL0, gB0, gL3, gB3)
  }
#undef STAGE
#undef REFRESH
#undef STEPK
#undef PREF

  // end = logaddexp(al[2*len], al[2*len-1]) from owned states
  if (s0 >= o0 && s0 < o1 && s0 == 2 * len) fin[0] = a0;
  if (s1 >= o0 && s1 < o1 && s1 == 2 * len - 1) fin[1] = a1;
  __syncthreads();
  if (tid == 0) {
    float a = fin[0], c = fin[1];
    float m = fmaxf(a, c);
    float e = m + __builtin_log2f(__builtin_exp2f(a - m) + __builtin_exp2f(c - m));
    ends[hyp * BB + b] = e;
  }
}

// ---------------------------------------------------------------------------
// Kernel 3: out[b] = (end_hyp' - end_gt') * ln2 + 1.0  (log2-domain ends)
// ---------------------------------------------------------------------------
__global__ void final_kernel(const float* __restrict__ ends,
                             float* __restrict__ out) {
  int b = threadIdx.x;
  if (b < BB) out[b] = (ends[BB + b] - ends[b]) * LN2F + 1.0f;
}

extern "C" void kernel_launch(void* const* d_in, const int* in_sizes, int n_in,
                              void* d_out, int out_size, void* d_ws,
                              size_t ws_size, hipStream_t stream) {
  const float* acts = (const float*)d_in[0];
  const int* labels = (const int*)d_in[1];
  const int* act_lens = (const int*)d_in[2];
  const int* label_lens = (const int*)d_in[3];
  float* out = (float*)d_out;

  char* ws = (char*)d_ws;
  int* dec = (int*)ws;                                          // B*LCAP ints
  int* dec_lens = (int*)(ws + (size_t)BB * LCAP * 4);           // B ints
  float* ends = (float*)(ws + (size_t)BB * LCAP * 4 + BB * 4);  // 2*B floats

  decode_kernel<<<dim3(BB), dim3(256), 0, stream>>>(acts, act_lens, dec, dec_lens);
  ctc_kernel<<<dim3(2 * BB), dim3(1024), 0, stream>>>(
      acts, labels, act_lens, label_lens, dec, dec_lens, ends);
  final_kernel<<<dim3(1), dim3(128), 0, stream>>>(ends, out);
}